// Round 3
// baseline (217.834 us; speedup 1.0000x reference)
//
#include <hip/hip_runtime.h>
#include <hip/hip_bf16.h>
#include <stdint.h>

typedef __attribute__((ext_vector_type(4))) float f32x4;
typedef __attribute__((ext_vector_type(8))) short short8;
typedef __attribute__((ext_vector_type(4))) unsigned short u16x4;

#define DEV __device__ __forceinline__
#define MFMA16(a, b, c) __builtin_amdgcn_mfma_f32_16x16x32_bf16(a, b, c, 0, 0, 0)

DEV unsigned short f2b(float x) {
  union { float f; uint32_t u; } c; c.f = x;
  uint32_t r = (c.u + 0x7fffu + ((c.u >> 16) & 1u)) >> 16;
  return (unsigned short)r;
}

DEV void gload_lds16(const void* g, void* l) {
  __builtin_amdgcn_global_load_lds((const __attribute__((address_space(1))) void*)g,
                                   (__attribute__((address_space(3))) void*)l, 16, 0, 0);
}

// ---------------- kernel 1: fp32 -> bf16 conversions ----------------
__global__ __launch_bounds__(256) void prep_k(
    const float* __restrict__ x, const float* __restrict__ wproj,
    const float* __restrict__ wg, const float* __restrict__ wo,
    unsigned short* __restrict__ Xbf, unsigned short* __restrict__ Wbf,
    unsigned short* __restrict__ Wobf) {
  int i = blockIdx.x * 256 + threadIdx.x;  // one float4 per thread, exact fit
  const float* src; unsigned short* dst;
  if (i < 524288)               { src = x     + (size_t)i * 4;                  dst = Xbf + (size_t)i * 4; }
  else if (i < 524288 + 786432) { int j = i - 524288;            src = wproj + (size_t)j * 4; dst = Wbf + (size_t)j * 4; }
  else if (i < 524288 + 786432 + 262144) { int j = i - (524288 + 786432); src = wg + (size_t)j * 4; dst = Wbf + 3145728 + (size_t)j * 4; }
  else                          { int j = i - (524288 + 786432 + 262144); src = wo + (size_t)j * 4; dst = Wobf + (size_t)j * 4; }
  f32x4 v = *(const f32x4*)src;
  u16x4 o; o.x = f2b(v.x); o.y = f2b(v.y); o.z = f2b(v.z); o.w = f2b(v.w);
  *(u16x4*)dst = o;
}

// ---------------- shared GEMM core: C[128x128] = A[128xK] * B[128xK]^T, K=1024 ----
DEV void gemm_stage(char* sm, const unsigned short* A, const unsigned short* Bw,
                    int tileMrow, int tileNrow, int buf, int kt, int lane, int wid) {
  const char* gA = (const char*)A;
  const char* gB = (const char*)Bw;
#pragma unroll
  for (int i = 0; i < 2; ++i) {
    int c = wid * 2 + i;                 // chunk 0..7, 1KB each (16 rows x 64B)
    int off = c * 1024 + lane * 16;
    int r = off >> 6, cb = off & 63;
    const char* srcA = gA + ((size_t)(tileMrow + r) * 2048) + kt * 64 + cb;
    gload_lds16(srcA, sm + buf * 8192 + c * 1024);
    const char* srcB = gB + ((size_t)(tileNrow + r) * 2048) + kt * 64 + cb;
    gload_lds16(srcB, sm + 16384 + buf * 8192 + c * 1024);
  }
}

DEV void gemm_main(const unsigned short* A, const unsigned short* Bw,
                   int tileMrow, int tileNrow, f32x4 acc[4][4], char* sm) {
  int tid = threadIdx.x, lane = tid & 63, wid = tid >> 6;
  int wr = wid >> 1, wc = wid & 1;
  gemm_stage(sm, A, Bw, tileMrow, tileNrow, 0, 0, lane, wid);
  for (int kt = 0; kt < 32; ++kt) {
    __syncthreads();
    if (kt < 31) gemm_stage(sm, A, Bw, tileMrow, tileNrow, (kt + 1) & 1, kt + 1, lane, wid);
    int ab = (kt & 1) * 8192;
    int rb = (lane & 15) * 64 + ((lane >> 4) * 16);
    short8 af[4], bf[4];
#pragma unroll
    for (int mi = 0; mi < 4; ++mi)
      af[mi] = *(const short8*)(sm + ab + (wr * 64 + mi * 16) * 64 + rb);
#pragma unroll
    for (int ni = 0; ni < 4; ++ni)
      bf[ni] = *(const short8*)(sm + 16384 + ab + (wc * 64 + ni * 16) * 64 + rb);
#pragma unroll
    for (int mi = 0; mi < 4; ++mi)
#pragma unroll
      for (int ni = 0; ni < 4; ++ni)
        acc[mi][ni] = MFMA16(af[mi], bf[ni], acc[mi][ni]);
  }
}

// ---------------- kernel 2: QKV+gate projection ----------------
__global__ __launch_bounds__(256) void gemm_qkvg_k(
    const unsigned short* __restrict__ Xbf, const unsigned short* __restrict__ Wbf,
    unsigned short* __restrict__ Qb, unsigned short* __restrict__ Kb,
    unsigned short* __restrict__ Vt, float* __restrict__ G,
    const float* __restrict__ bg) {
  __shared__ char sm[32768];
  int bid = blockIdx.x;
  int swz = (bid & 7) * 64 + (bid >> 3);  // XCD-chunked swizzle, 512 blocks
  int tileM = swz >> 5, tileN = swz & 31;
  f32x4 acc[4][4] = {};
  gemm_main(Xbf, Wbf, tileM * 128, tileN * 128, acc, sm);
  int lane = threadIdx.x & 63, wid = threadIdx.x >> 6;
  int wr = wid >> 1, wc = wid & 1;
#pragma unroll
  for (int mi = 0; mi < 4; ++mi)
#pragma unroll
    for (int ni = 0; ni < 4; ++ni)
#pragma unroll
      for (int j = 0; j < 4; ++j) {
        int row = tileM * 128 + wr * 64 + mi * 16 + ((lane >> 4) << 2) + j;
        int col = tileN * 128 + wc * 64 + ni * 16 + (lane & 15);
        float v = acc[mi][ni][j];
        int b = row >> 10, l = row & 1023;
        if (col < 3072) {
          int h = col / 192, r = col - h * 192;
          size_t base = ((size_t)(b * 16 + h) * 1024 + l) * 64;
          if (r < 64)        Qb[base + r] = f2b(v * 0.125f);
          else if (r < 128)  Kb[base + (r - 64)] = f2b(v);
          else               Vt[((size_t)(b * 16 + h) * 64 + (r - 128)) * 1024 + l] = f2b(v);
        } else {
          int e = col - 3072;
          float s = v + bg[e];
          G[(size_t)row * 1024 + e] = 1.f / (1.f + __expf(-s));
        }
      }
}

// ---------------- kernel 3: attention ----------------
// Block: (b, hg: 2 heads, qt: 16 q-rows), 4 waves x 256 lk. Raw bias read as
// float2 (both heads); 8 hg-blocks of a slab share cachelines via same-XCD L2.
__global__ __launch_bounds__(256) void attn_k(
    const unsigned short* __restrict__ Qb, const unsigned short* __restrict__ Kb,
    const unsigned short* __restrict__ Vt, const float* __restrict__ bias,
    const float* __restrict__ G, unsigned short* __restrict__ Ybf,
    float* __restrict__ outa) {
  __shared__ char sm[51200];
  int tid = threadIdx.x, lane = tid & 63, w = tid >> 6;
  int la = lane & 15, lg = lane >> 4;
  int bid = blockIdx.x;
  // bid = sHi*64 + hg*8 + x ; slab s = sHi*8 + x ; xcd(bid)=bid%8=s%8
  int x = bid & 7, hg = (bid >> 3) & 7, sHi = bid >> 6;
  int s = sHi * 8 + x;
  int b = s >> 6, qt = s & 63;
  int h0 = hg * 2, lq0 = qt * 16;
  int lk0 = w * 256;
  size_t bh0 = (size_t)(b * 16 + h0);
  const unsigned short* Q0 = Qb + bh0 * 65536;
  const unsigned short* K0 = Kb + bh0 * 65536;
  const unsigned short* V0 = Vt + bh0 * 65536;  // Vt[bh][c][lk]
  const float* biasB = bias + ((size_t)b << 24) + h0;

  short8 qf[2][2];
#pragma unroll
  for (int h = 0; h < 2; ++h)
#pragma unroll
    for (int ks = 0; ks < 2; ++ks)
      qf[h][ks] = *(const short8*)(Q0 + (size_t)h * 65536 + (size_t)(lq0 + la) * 64 + ks * 32 + lg * 8);

  f32x4 acc[2][16] = {};
#pragma unroll
  for (int nf = 0; nf < 16; ++nf) {
    int kb = lk0 + nf * 16;
    const unsigned short* kr = K0 + (size_t)(kb + la) * 64 + lg * 8;
    short8 kf00 = *(const short8*)kr;
    short8 kf01 = *(const short8*)(kr + 32);
    short8 kf10 = *(const short8*)(kr + 65536);
    short8 kf11 = *(const short8*)(kr + 65536 + 32);
    acc[0][nf] = MFMA16(qf[0][0], kf00, acc[0][nf]);
    acc[0][nf] = MFMA16(qf[0][1], kf01, acc[0][nf]);
    acc[1][nf] = MFMA16(qf[1][0], kf10, acc[1][nf]);
    acc[1][nf] = MFMA16(qf[1][1], kf11, acc[1][nf]);
    int lkl = kb + la;
#pragma unroll
    for (int j = 0; j < 4; ++j) {
      int lq = lq0 + lg * 4 + j;
      float2 bv = *(const float2*)(biasB + ((size_t)lq << 14) + ((size_t)lkl << 4));
      acc[0][nf][j] += bv.x;
      acc[1][nf][j] += bv.y;
    }
  }

  // ---- softmax over full row (1024 lk across 4 waves); rows = (h, lq) = 32 ----
  float* redm = (float*)(sm + 50176);  // [4][32]
  float* reds = (float*)(sm + 50688);  // [4][32]
  float rmax[2][4];
#pragma unroll
  for (int h = 0; h < 2; ++h)
#pragma unroll
    for (int j = 0; j < 4; ++j) {
      float m = acc[h][0][j];
#pragma unroll
      for (int nf = 1; nf < 16; ++nf) m = fmaxf(m, acc[h][nf][j]);
#pragma unroll
      for (int d = 1; d < 16; d <<= 1) m = fmaxf(m, __shfl_xor(m, d));
      rmax[h][j] = m;
    }
  if (la == 0) {
#pragma unroll
    for (int h = 0; h < 2; ++h)
#pragma unroll
      for (int j = 0; j < 4; ++j) redm[w * 32 + h * 16 + lg * 4 + j] = rmax[h][j];
  }
  __syncthreads();
  float rsum[2][4];
#pragma unroll
  for (int h = 0; h < 2; ++h)
#pragma unroll
    for (int j = 0; j < 4; ++j) {
      int r = h * 16 + lg * 4 + j;
      float m = fmaxf(fmaxf(redm[r], redm[32 + r]), fmaxf(redm[64 + r], redm[96 + r]));
      float ss = 0.f;
#pragma unroll
      for (int nf = 0; nf < 16; ++nf) {
        float e = __expf(acc[h][nf][j] - m);
        acc[h][nf][j] = e;
        ss += e;
      }
#pragma unroll
      for (int d = 1; d < 16; d <<= 1) ss += __shfl_xor(ss, d);
      rsum[h][j] = ss;
    }
  if (la == 0) {
#pragma unroll
    for (int h = 0; h < 2; ++h)
#pragma unroll
      for (int j = 0; j < 4; ++j) reds[w * 32 + h * 16 + lg * 4 + j] = rsum[h][j];
  }
  __syncthreads();
  float rinv[2][4];
#pragma unroll
  for (int h = 0; h < 2; ++h)
#pragma unroll
    for (int j = 0; j < 4; ++j) {
      int r = h * 16 + lg * 4 + j;
      rinv[h][j] = 1.f / (reds[r] + reds[32 + r] + reds[64 + r] + reds[96 + r]);
    }

  // ---- per-wave: probs (transposed store) + PV, in 64-lk chunks ----
  char* pb = sm + w * 4096;                     // [32 rows][64 lk2] bf16, XOR-swizzled
  float* ot = (float*)(sm + 16384 + w * 8448);  // [64 lk2][33] f32 (pad)
  f32x4 yacc[2][4] = {};
#pragma unroll
  for (int cc = 0; cc < 4; ++cc) {
#pragma unroll
    for (int h = 0; h < 2; ++h)
#pragma unroll
      for (int nfl = 0; nfl < 4; ++nfl)
#pragma unroll
        for (int j = 0; j < 4; ++j) {
          int nf = cc * 4 + nfl;
          float v = acc[h][nf][j] * rinv[h][j];
          int row = h * 16 + lg * 4 + j;   // (h, lq) in [0,32)
          int lk2 = nfl * 16 + la;         // [0,64)
          *(unsigned short*)(pb + ((row * 128 + lk2 * 2) ^ ((row & 7) << 4))) = f2b(v);
          ot[lk2 * 33 + row] = v;
        }
    // transposed prob stores: outa[b][lk][h0+dh][lq0..lq0+16)
#pragma unroll
    for (int it = 0; it < 8; ++it) {
      int idx = it * 64 + lane;
      int q4 = idx & 3, dh = (idx >> 2) & 1, lk2 = idx >> 3;
      f32x4 ov;
#pragma unroll
      for (int i = 0; i < 4; ++i) ov[i] = ot[lk2 * 33 + dh * 16 + q4 * 4 + i];
      size_t lkG = (size_t)(lk0 + cc * 64 + lk2);
      *(f32x4*)(outa + ((size_t)b << 24) + (lkG << 14) + ((size_t)(h0 + dh) << 10) + lq0 + q4 * 4) = ov;
    }
    // PV for this chunk
#pragma unroll
    for (int ks = 0; ks < 2; ++ks) {
      short8 pa[2];
#pragma unroll
      for (int h = 0; h < 2; ++h) {
        int row = h * 16 + la;
        pa[h] = *(const short8*)(pb + ((row * 128 + ks * 64 + lg * 16) ^ ((row & 7) << 4)));
      }
#pragma unroll
      for (int ni = 0; ni < 4; ++ni)
#pragma unroll
        for (int h = 0; h < 2; ++h) {
          short8 vf = *(const short8*)(V0 + (size_t)h * 65536 +
                                       (size_t)(ni * 16 + la) * 1024 + lk0 + cc * 64 + ks * 32 + lg * 8);
          yacc[h][ni] = MFMA16(pa[h], vf, yacc[h][ni]);
        }
    }
  }

  // ---- cross-wave y reduction + gate ----
  __syncthreads();  // all ot/pb reads done
#pragma unroll
  for (int h = 0; h < 2; ++h)
#pragma unroll
    for (int ni = 0; ni < 4; ++ni)
#pragma unroll
      for (int j = 0; j < 4; ++j) {
        int row = h * 16 + lg * 4 + j, c = ni * 16 + la;
        ((float*)(sm + 16384 + w * 8448))[row * 65 + c] = yacc[h][ni][j];
      }
  __syncthreads();
#pragma unroll
  for (int rr = 0; rr < 8; ++rr) {
    int e = rr * 256 + tid;           // [0, 2048)
    int row = e >> 6, c = e & 63;
    float sum = 0.f;
#pragma unroll
    for (int w4 = 0; w4 < 4; ++w4) sum += ((const float*)(sm + 16384 + w4 * 8448))[row * 65 + c];
    int h = h0 + (row >> 4), lq = lq0 + (row & 15);
    size_t gi = (((size_t)b * 1024 + lq) << 10) + h * 64 + c;
    Ybf[gi] = f2b(sum * G[gi]);
  }
}

// ---------------- kernel 4: output projection ----------------
__global__ __launch_bounds__(256) void gemm_out_k(
    const unsigned short* __restrict__ Ybf, const unsigned short* __restrict__ Wobf,
    const float* __restrict__ bo, float* __restrict__ outy) {
  __shared__ char sm[32768];
  int bid = blockIdx.x;
  int swz = (bid & 7) * 16 + (bid >> 3);  // 128 blocks
  int tileM = swz >> 3, tileN = swz & 7;
  f32x4 acc[4][4] = {};
  gemm_main(Ybf, Wobf, tileM * 128, tileN * 128, acc, sm);
  int lane = threadIdx.x & 63, wid = threadIdx.x >> 6;
  int wr = wid >> 1, wc = wid & 1;
#pragma unroll
  for (int mi = 0; mi < 4; ++mi)
#pragma unroll
    for (int ni = 0; ni < 4; ++ni)
#pragma unroll
      for (int j = 0; j < 4; ++j) {
        int row = tileM * 128 + wr * 64 + mi * 16 + ((lane >> 4) << 2) + j;
        int col = tileN * 128 + wc * 64 + ni * 16 + (lane & 15);
        outy[(size_t)row * 1024 + col] = acc[mi][ni][j] + bo[col];
      }
}

extern "C" void kernel_launch(void* const* d_in, const int* in_sizes, int n_in,
                              void* d_out, int out_size, void* d_ws, size_t ws_size,
                              hipStream_t stream) {
  const float* x     = (const float*)d_in[0];
  const float* bias  = (const float*)d_in[1];
  const float* wproj = (const float*)d_in[2];
  const float* wo    = (const float*)d_in[3];
  const float* bo    = (const float*)d_in[4];
  const float* wg    = (const float*)d_in[5];
  const float* bg    = (const float*)d_in[6];
  float* outy = (float*)d_out;
  float* outa = outy + 2097152;  // y (2M floats), then attn (B,Lk,H,Lq)

  char* ws = (char*)d_ws;
  unsigned short* Xbf  = (unsigned short*)(ws);
  unsigned short* Wbf  = (unsigned short*)(ws + 4  * 1024 * 1024);
  unsigned short* Wobf = (unsigned short*)(ws + 12 * 1024 * 1024);
  unsigned short* Qb   = (unsigned short*)(ws + 14 * 1024 * 1024);
  unsigned short* Kb   = (unsigned short*)(ws + 18 * 1024 * 1024);
  unsigned short* Vt   = (unsigned short*)(ws + 22 * 1024 * 1024);
  float*          G    = (float*)        (ws + 26 * 1024 * 1024);
  unsigned short* Ybf  = (unsigned short*)(ws + 34 * 1024 * 1024);
  if (ws_size < (size_t)38 * 1024 * 1024) return;  // need 38MB scratch

  prep_k<<<dim3(7168), dim3(256), 0, stream>>>(x, wproj, wg, wo, Xbf, Wbf, Wobf);
  gemm_qkvg_k<<<dim3(512), dim3(256), 0, stream>>>(Xbf, Wbf, Qb, Kb, Vt, G, bg);
  attn_k<<<dim3(1024), dim3(256), 0, stream>>>(Qb, Kb, Vt, bias, G, Ybf, outa);
  gemm_out_k<<<dim3(128), dim3(256), 0, stream>>>(Ybf, Wobf, bo, outy);
}